// Round 7
// baseline (242.281 us; speedup 1.0000x reference)
//
#include <hip/hip_runtime.h>
#include <hip/hip_bf16.h>
#include <math.h>

// CoSent clustering loss on MI355X — round 7.
// Diagnosis r4-r6: occupancy 17% (2 waves/SIMD) + tiny per-block quantum made
// every latency chain visible; A-load placement was irrelevant.
// New structure: 256x256 triangular tiles (528 blocks), 512 threads (8 waves,
// 4x2), B staged in K-quarter (64) double-buffer (2x32KB), rowsc/colsc
// union-overlaid on bufB[0] -> ~66KB LDS -> 2 blocks/CU = 16 waves/CU (50%).
// Per-block MFMA x4. Fused exp/mask epilogue with DPP row-reduce + col-side
// (symmetry) -> packed bf16 partials -> reduce + finalize.

typedef __bf16 bf16;
typedef __attribute__((ext_vector_type(4))) __bf16 bf16x4;
typedef __attribute__((ext_vector_type(8))) __bf16 bf16x8;
typedef __attribute__((ext_vector_type(4))) float f32x4;

#define N_EMB 8192
#define D_EMB 256
#define NUM_LABELS 128
#define PAN 256
#define KSUB 64
#define NPAN (N_EMB / PAN)           // 32
#define NTRI (NPAN * (NPAN + 1) / 2) // 528

// ---- DPP 16-lane reduction helpers ----
template <int CTRL>
__device__ __forceinline__ float dpp_add(float x) {
    int y = __builtin_amdgcn_update_dpp(0, __builtin_bit_cast(int, x),
                                        CTRL, 0xF, 0xF, false);
    return x + __builtin_bit_cast(float, y);
}
__device__ __forceinline__ float red16(float x) {
    x = dpp_add<0xB1>(x);    // quad_perm xor1
    x = dpp_add<0x4E>(x);    // quad_perm xor2
    x = dpp_add<0x124>(x);   // row_ror:4
    x = dpp_add<0x128>(x);   // row_ror:8
    return x;
}

__device__ __forceinline__ unsigned packbf(float a, float b) {
    unsigned ua = __builtin_bit_cast(unsigned, a);
    unsigned ub = __builtin_bit_cast(unsigned, b);
    ua += 0x7FFFu + ((ua >> 16) & 1u);   // RTNE to bf16
    ub += 0x7FFFu + ((ub >> 16) & 1u);
    return (ua >> 16) | (ub & 0xFFFF0000u);
}

// ---------------------------------------------------------------- normalize
__global__ __launch_bounds__(256) void normalize_kernel(const float* __restrict__ emb,
                                                        bf16* __restrict__ e16) {
    const int wid = threadIdx.x >> 6, lane = threadIdx.x & 63;
    const int row = blockIdx.x * 4 + wid;
    const f32x4 x = *(const f32x4*)(emb + (size_t)row * D_EMB + lane * 4);
    float ss = x[0]*x[0] + x[1]*x[1] + x[2]*x[2] + x[3]*x[3];
    #pragma unroll
    for (int off = 32; off >= 1; off >>= 1) ss += __shfl_xor(ss, off);
    const float r = 1.0f / fmaxf(sqrtf(ss), 1e-12f);
    bf16x4 o;
    #pragma unroll
    for (int i = 0; i < 4; ++i) o[i] = (bf16)(x[i] * r);
    *(bf16x4*)(e16 + (size_t)row * D_EMB + lane * 4) = o;
}

// ------------------------------------------------------- async global->LDS
__device__ __forceinline__ void gload_lds16(const bf16* gsrc, bf16* ldst) {
    __builtin_amdgcn_global_load_lds(
        (const __attribute__((address_space(1))) void*)gsrc,
        (__attribute__((address_space(3))) void*)ldst, 16, 0, 0);
}

// ----------------------------------------------------------------- main GEMM
// 8 waves as 4(wm: 64-row groups) x 2(wn: 128-col halves); per-wave output
// 64x128 = 4x8 frags of 16x16x32. B LDS per quarter: [256 cols][8 kchunks][8],
// chunk slot XOR-swizzled (kc ^ (col&7)) via pre-swizzled global source.
__global__ __launch_bounds__(512, 4) void cosent_main(const bf16* __restrict__ e,
                                                      const int* __restrict__ labels,
                                                      const float* __restrict__ scale,
                                                      unsigned* __restrict__ wsAB) {
    __shared__ bf16 bufB[2][PAN * KSUB];    // 2 x 32 KB
    __shared__ int labR[PAN], labC[PAN];
    // overlay on bufB[0] (safe: last quarter reads bufB[1]):
    //   rowsc[wn][row][2] : uni[0      .. 1023]
    //   colsc[wm][col][2] : uni[1024   .. 3071]
    float* uni = (float*)&bufB[0][0];

    // triangular decode (closed form + exact fixup); offset(by)=by*(65-by)/2
    const int idx = blockIdx.x;
    int by = (int)((65.0f - sqrtf(65.0f * 65.0f - 8.0f * (float)idx)) * 0.5f);
    by = by < 0 ? 0 : (by > 31 ? 31 : by);
    while (by > 0 && by * (65 - by) / 2 > idx) --by;
    while (by < 31 && (by + 1) * (64 - by) / 2 <= idx) ++by;
    const int bx = by + (idx - by * (65 - by) / 2);
    const bool diag = (bx == by);
    const int rowBase = by * PAN, colBase = bx * PAN;

    const int tid = threadIdx.x, lane = tid & 63, wid = tid >> 6;
    const int wm = wid >> 1, wn = wid & 1;
    const int rr = lane & 15, kh = lane >> 4;

    if (tid < PAN) labR[tid] = labels[rowBase + tid];
    else           labC[tid - PAN] = labels[colBase + tid - PAN];

    // stage one K-quarter of the B panel into buffer b at k-offset k0.
    // q = i*512+tid ; col r = q>>3 ; LDS slot q&7 holds source chunk (q&7)^(r&7).
    auto stage = [&](int b, int k0) {
        #pragma unroll
        for (int i = 0; i < 4; ++i) {
            const int qb = i * 512 + wid * 64;   // wave-uniform chunk base
            const int q  = qb + lane;
            const int r  = q >> 3;
            const int kc = (q & 7) ^ (r & 7);    // pre-swizzled source chunk
            gload_lds16(e + (size_t)(colBase + r) * D_EMB + k0 + kc * 8,
                        &bufB[b][qb * 8]);
        }
    };

    f32x4 acc[4][8];
    #pragma unroll
    for (int i = 0; i < 4; ++i)
        #pragma unroll
        for (int j = 0; j < 8; ++j) acc[i][j] = (f32x4){0.f, 0.f, 0.f, 0.f};

    stage(0, 0);
    __syncthreads();

    const bf16* aB = e + (size_t)(rowBase + wm * 64 + rr) * D_EMB + kh * 8;

    #pragma unroll
    for (int q = 0; q < 4; ++q) {            // K = 256 = 4 * KSUB(64)
        if (q < 3) stage((q + 1) & 1, (q + 1) * KSUB);
        // A fragments for this quarter (8 x 16B per thread, L2/L1-resident)
        bf16x8 af[2][4];
        #pragma unroll
        for (int c = 0; c < 2; ++c)
            #pragma unroll
            for (int mi = 0; mi < 4; ++mi)
                af[c][mi] = *(const bf16x8*)(aB + (size_t)mi * 16 * D_EMB
                                                + q * KSUB + c * 32);
        __builtin_amdgcn_s_setprio(1);
        #pragma unroll
        for (int c = 0; c < 2; ++c) {
            #pragma unroll
            for (int ni = 0; ni < 8; ++ni) {
                const int colL = wn * 128 + ni * 16 + rr;
                const int kc = c * 4 + kh;
                const bf16x8 bg = *(const bf16x8*)
                    &bufB[q & 1][(colL * 8 + (kc ^ (colL & 7))) * 8];
                #pragma unroll
                for (int mi = 0; mi < 4; ++mi)
                    acc[mi][ni] = __builtin_amdgcn_mfma_f32_16x16x32_bf16(
                        af[c][mi], bg, acc[mi][ni], 0, 0, 0);
            }
        }
        __builtin_amdgcn_s_setprio(0);
        __syncthreads();
    }

    // ------------- fused epilogue: one exp per element, row + col partials
    const float s = *scale;
    int lcv[8];
    #pragma unroll
    for (int ni = 0; ni < 8; ++ni) lcv[ni] = labC[wn * 128 + ni * 16 + rr];
    float colA[8], colB[8];
    #pragma unroll
    for (int ni = 0; ni < 8; ++ni) { colA[ni] = 0.f; colB[ni] = 0.f; }

    #pragma unroll
    for (int mi = 0; mi < 4; ++mi) {
        #pragma unroll
        for (int r = 0; r < 4; ++r) {
            const int rowL = wm * 64 + mi * 16 + kh * 4 + r;
            const int lr = labR[rowL];
            float asum = 0.f, bsum = 0.f;
            #pragma unroll
            for (int ni = 0; ni < 8; ++ni) {
                const int colL = wn * 128 + ni * 16 + rr;
                const float val = acc[mi][ni][r] * s;
                const bool pos = (lr == lcv[ni]);
                float ex = __expf(pos ? -val : val);
                if (diag && rowL == colL) ex = 0.f;   // exclude self-pairs
                if (pos) { asum += ex; colA[ni] += ex; }
                else     { bsum += ex; colB[ni] += ex; }
            }
            asum = red16(asum);
            bsum = red16(bsum);
            if (rr == 0) {
                uni[(wn * PAN + rowL) * 2 + 0] = asum;
                uni[(wn * PAN + rowL) * 2 + 1] = bsum;
            }
        }
    }

    if (!diag) {   // col-side (transposed contribution via symmetry)
        #pragma unroll
        for (int ni = 0; ni < 8; ++ni) {
            float a = colA[ni], b = colB[ni];
            a += __shfl_xor(a, 16); a += __shfl_xor(a, 32);
            b += __shfl_xor(b, 16); b += __shfl_xor(b, 32);
            if (lane < 16) {
                const int colL = wn * 128 + ni * 16 + lane;
                uni[1024 + (wm * PAN + colL) * 2 + 0] = a;
                uni[1024 + (wm * PAN + colL) * 2 + 1] = b;
            }
        }
    }
    __syncthreads();

    if (tid < PAN) {
        const float ra = uni[(0 * PAN + tid) * 2 + 0] + uni[(1 * PAN + tid) * 2 + 0];
        const float rb = uni[(0 * PAN + tid) * 2 + 1] + uni[(1 * PAN + tid) * 2 + 1];
        wsAB[(size_t)bx * N_EMB + rowBase + tid] = packbf(ra, rb);
        if (!diag) {
            float ca = 0.f, cb = 0.f;
            #pragma unroll
            for (int w = 0; w < 4; ++w) {
                ca += uni[1024 + (w * PAN + tid) * 2 + 0];
                cb += uni[1024 + (w * PAN + tid) * 2 + 1];
            }
            wsAB[(size_t)by * N_EMB + colBase + tid] = packbf(ca, cb);
        }
    }
}

// --------------------------------------------------- per-row + segment reduce
__global__ __launch_bounds__(256) void reduce_rows(const unsigned* __restrict__ wsAB,
                                                   const int* __restrict__ labels,
                                                   float* __restrict__ part) {
    __shared__ float A[NUM_LABELS], B[NUM_LABELS];
    __shared__ int C[NUM_LABELS];
    const int tid = threadIdx.x;
    if (tid < NUM_LABELS) { A[tid] = 0.f; B[tid] = 0.f; C[tid] = 0; }
    __syncthreads();
    const int row = blockIdx.x * 256 + tid;
    float a = 0.f, b = 0.f;
    #pragma unroll
    for (int p = 0; p < NPAN; ++p) {
        const unsigned u = wsAB[(size_t)p * N_EMB + row];
        a += __builtin_bit_cast(float, u << 16);
        b += __builtin_bit_cast(float, u & 0xFFFF0000u);
    }
    const int l = labels[row];
    atomicAdd(&A[l], a);
    atomicAdd(&B[l], b);
    atomicAdd(&C[l], 1);
    __syncthreads();
    if (tid < NUM_LABELS) {
        float* p = part + ((size_t)blockIdx.x * NUM_LABELS + tid) * 3;
        p[0] = A[tid]; p[1] = B[tid]; p[2] = (float)C[tid];
    }
}

// ----------------------------------------------------------------- finalize
__global__ __launch_bounds__(128) void finalize_kernel(const float* __restrict__ part,
                                                       float* __restrict__ out) {
    const int tid = threadIdx.x;   // label id
    float A = 0.f, B = 0.f, c = 0.f;
    #pragma unroll
    for (int blk = 0; blk < 32; ++blk) {
        const float* p = part + ((size_t)blk * NUM_LABELS + tid) * 3;
        A += p[0]; B += p[1]; c += p[2];
    }
    float v = (c >= 2.f) ? A * B : 0.f;
    #pragma unroll
    for (int off = 32; off >= 1; off >>= 1) v += __shfl_xor(v, off);
    __shared__ float w2[2];
    if ((tid & 63) == 0) w2[tid >> 6] = v;
    __syncthreads();
    if (tid == 0) out[0] = logf(1.0f + w2[0] + w2[1]);
}

// ------------------------------------------------------------------ launcher
extern "C" void kernel_launch(void* const* d_in, const int* in_sizes, int n_in,
                              void* d_out, int out_size, void* d_ws, size_t ws_size,
                              hipStream_t stream) {
    const float* emb    = (const float*)d_in[0];
    const int*   labels = (const int*)d_in[1];
    const float* scale  = (const float*)d_in[2];
    float* out = (float*)d_out;

    bf16*     e16  = (bf16*)d_ws;                                     // 4 MB
    unsigned* wsAB = (unsigned*)((char*)d_ws + (size_t)N_EMB * D_EMB * sizeof(bf16)); // 1 MB
    float*    part = (float*)((char*)wsAB + (size_t)NPAN * N_EMB * sizeof(unsigned)); // 48 KB

    normalize_kernel<<<N_EMB / 4, 256, 0, stream>>>(emb, e16);
    cosent_main<<<NTRI, 512, 0, stream>>>(e16, labels, scale, wsAB);
    reduce_rows<<<N_EMB / 256, 256, 0, stream>>>(wsAB, labels, part);
    finalize_kernel<<<1, 128, 0, stream>>>(part, out);
}

// Round 8
// 73.684 us; speedup vs baseline: 3.2881x; 3.2881x over previous
//
#include <hip/hip_runtime.h>
#include <hip/hip_bf16.h>
#include <math.h>

// CoSent clustering loss on MI355X — round 8.
// Lesson r7: unified VGPR/AGPR file — acc counts against launch_bounds cap.
// Structure: 544 run-blocks; each owns a 128-row panel (A staged full-K in
// LDS once) and up to 8 consecutive 64-col subtiles (B 32KB double-buffered,
// staged one-ahead). K-loop pure ds_read+MFMA, one barrier per subtile.
// Row partials accumulate in registers across the run (red16 once per run);
// col partials via shfl+LDS per subtile (symmetry, triangular coverage).

typedef __bf16 bf16;
typedef __attribute__((ext_vector_type(4))) __bf16 bf16x4;
typedef __attribute__((ext_vector_type(8))) __bf16 bf16x8;
typedef __attribute__((ext_vector_type(4))) float f32x4;

#define N_EMB 8192
#define D_EMB 256
#define NUM_LABELS 128
#define PAN 128              // row-panel height
#define CPAN 64              // column subtile width
#define NPAN 64              // number of 128-row panels
#define NRUN 544             // sum over by of ceil(2*(64-by)/8)

// ---- DPP 16-lane reduction helpers ----
template <int CTRL>
__device__ __forceinline__ float dpp_add(float x) {
    int y = __builtin_amdgcn_update_dpp(0, __builtin_bit_cast(int, x),
                                        CTRL, 0xF, 0xF, false);
    return x + __builtin_bit_cast(float, y);
}
__device__ __forceinline__ float red16(float x) {
    x = dpp_add<0xB1>(x);    // quad_perm xor1
    x = dpp_add<0x4E>(x);    // quad_perm xor2
    x = dpp_add<0x124>(x);   // row_ror:4
    x = dpp_add<0x128>(x);   // row_ror:8
    return x;
}

__device__ __forceinline__ unsigned packbf(float a, float b) {
    unsigned ua = __builtin_bit_cast(unsigned, a);
    unsigned ub = __builtin_bit_cast(unsigned, b);
    ua += 0x7FFFu + ((ua >> 16) & 1u);   // RTNE to bf16
    ub += 0x7FFFu + ((ub >> 16) & 1u);
    return (ua >> 16) | (ub & 0xFFFF0000u);
}

// ---------------------------------------------------------------- normalize
// Also zeroes wsAB (64 panels x 8192 rows = 512K words; grid 2048x256 = 1 each).
__global__ __launch_bounds__(256) void normalize_kernel(const float* __restrict__ emb,
                                                        bf16* __restrict__ e16,
                                                        unsigned* __restrict__ wsAB) {
    const int wid = threadIdx.x >> 6, lane = threadIdx.x & 63;
    const int row = blockIdx.x * 4 + wid;
    const f32x4 x = *(const f32x4*)(emb + (size_t)row * D_EMB + lane * 4);
    float ss = x[0]*x[0] + x[1]*x[1] + x[2]*x[2] + x[3]*x[3];
    #pragma unroll
    for (int off = 32; off >= 1; off >>= 1) ss += __shfl_xor(ss, off);
    const float r = 1.0f / fmaxf(sqrtf(ss), 1e-12f);
    bf16x4 o;
    #pragma unroll
    for (int i = 0; i < 4; ++i) o[i] = (bf16)(x[i] * r);
    *(bf16x4*)(e16 + (size_t)row * D_EMB + lane * 4) = o;
    wsAB[blockIdx.x * 256 + threadIdx.x] = 0u;
}

// ------------------------------------------------------- async global->LDS
__device__ __forceinline__ void gload_lds16(const bf16* gsrc, bf16* ldst) {
    __builtin_amdgcn_global_load_lds(
        (const __attribute__((address_space(1))) void*)gsrc,
        (__attribute__((address_space(3))) void*)ldst, 16, 0, 0);
}

// ----------------------------------------------------------------- main GEMM
// 8 waves: wm = wid>>1 (0..3, 32-row groups), wn = wid&1 (0..1, 32-col halves).
// Per-wave out 32x32 = 2x2 frags of 16x16x32 -> acc 16 regs.
// LDS layouts: buf[row/col][32 k-chunks][8 bf16], chunk slot XOR-swizzled
// (slot = kc ^ (rr&7)) via pre-swizzled global source.
__global__ __launch_bounds__(512, 2) void cosent_main(const bf16* __restrict__ e,
                                                      const int* __restrict__ labels,
                                                      const float* __restrict__ scale,
                                                      unsigned* __restrict__ wsAB) {
    __shared__ bf16 bufA[PAN * D_EMB];        // 64 KB
    __shared__ bf16 bufB[2][CPAN * D_EMB];    // 2 x 32 KB
    __shared__ int labR[PAN];
    __shared__ float colsc[2][4][CPAN][2];    // [parity][wm][col][a,b]  4 KB
    __shared__ float rowsc[2][PAN][2];        // [wn][row][a,b]          2 KB

    // run decode: nb(by) = ceil(2*(64-by)/8) = (67-by)>>2
    int rid = blockIdx.x, by = 0;
    while (rid >= ((67 - by) >> 2)) { rid -= (67 - by) >> 2; ++by; }
    const int j0 = rid * 8;                         // first subtile in this row
    const int nsub = 2 * (64 - by);
    const int len = min(8, nsub - j0);
    const int rowBase = by * PAN;
    const int bxFirst = by + (j0 >> 1);             // row-side output slot

    const int tid = threadIdx.x, lane = tid & 63, wid = tid >> 6;
    const int wm = wid >> 1, wn = wid & 1;
    const int rr = lane & 15, kh = lane >> 4;

    // ---- stage A panel (full K, once per run) ----
    #pragma unroll
    for (int i = 0; i < 8; ++i) {
        const int qb = i * 512 + wid * 64;          // wave-uniform chunk base
        const int q  = qb + lane;
        const int r  = q >> 5;
        const int kc = (q & 31) ^ (r & 7);          // pre-swizzled source chunk
        gload_lds16(e + (size_t)(rowBase + r) * D_EMB + kc * 8, &bufA[qb * 8]);
    }
    if (tid < PAN) labR[tid] = labels[rowBase + tid];

    auto stageB = [&](int buf, int cb0) {
        #pragma unroll
        for (int i = 0; i < 4; ++i) {
            const int qb = i * 512 + wid * 64;
            const int q  = qb + lane;
            const int cc = q >> 5;
            const int kc = (q & 31) ^ (cc & 7);
            gload_lds16(e + (size_t)(cb0 + cc) * D_EMB + kc * 8, &bufB[buf][qb * 8]);
        }
    };

    stageB(0, bxFirst * PAN + (j0 & 1) * CPAN);
    __syncthreads();

    // row labels for this wave's 8 rows (fixed across the run)
    int lrv[2][4];
    #pragma unroll
    for (int mi = 0; mi < 2; ++mi)
        #pragma unroll
        for (int r = 0; r < 4; ++r)
            lrv[mi][r] = labR[wm * 32 + mi * 16 + kh * 4 + r];

    const float s = *scale;
    float rowA[2][4], rowB[2][4];
    #pragma unroll
    for (int mi = 0; mi < 2; ++mi)
        #pragma unroll
        for (int r = 0; r < 4; ++r) { rowA[mi][r] = 0.f; rowB[mi][r] = 0.f; }

    for (int li = 0; li < len; ++li) {
        const int jg = j0 + li;
        const int bx = by + (jg >> 1);
        const int cb0 = bx * PAN + (jg & 1) * CPAN;  // global col base
        const bool diag = (bx == by);

        if (li + 1 < len) {                           // prefetch next B subtile
            const int jg2 = jg + 1;
            stageB((li + 1) & 1, (by + (jg2 >> 1)) * PAN + (jg2 & 1) * CPAN);
        }

        // ---- K-loop: pure LDS reads + MFMA ----
        f32x4 acc[2][2];
        #pragma unroll
        for (int mi = 0; mi < 2; ++mi)
            #pragma unroll
            for (int ni = 0; ni < 2; ++ni) acc[mi][ni] = (f32x4){0.f,0.f,0.f,0.f};

        const bf16* bb = &bufB[li & 1][0];
        #pragma unroll
        for (int t = 0; t < 8; ++t) {
            const int sl = (t * 4 + kh) ^ (rr & 7);
            bf16x8 af[2], bg[2];
            #pragma unroll
            for (int mi = 0; mi < 2; ++mi)
                af[mi] = *(const bf16x8*)&bufA[((wm*32 + mi*16 + rr) * 32 + sl) * 8];
            #pragma unroll
            for (int ni = 0; ni < 2; ++ni)
                bg[ni] = *(const bf16x8*)&bb[((wn*32 + ni*16 + rr) * 32 + sl) * 8];
            #pragma unroll
            for (int mi = 0; mi < 2; ++mi)
                #pragma unroll
                for (int ni = 0; ni < 2; ++ni)
                    acc[mi][ni] = __builtin_amdgcn_mfma_f32_16x16x32_bf16(
                        af[mi], bg[ni], acc[mi][ni], 0, 0, 0);
        }

        // ---- epilogue: exp/mask, reg row-accumulate, col partials ----
        int lcv[2];
        #pragma unroll
        for (int ni = 0; ni < 2; ++ni)
            lcv[ni] = labels[cb0 + wn * 32 + ni * 16 + rr];
        float cA[2] = {0.f, 0.f}, cB[2] = {0.f, 0.f};

        #pragma unroll
        for (int mi = 0; mi < 2; ++mi) {
            #pragma unroll
            for (int r = 0; r < 4; ++r) {
                const int grow = rowBase + wm * 32 + mi * 16 + kh * 4 + r;
                const int lr = lrv[mi][r];
                #pragma unroll
                for (int ni = 0; ni < 2; ++ni) {
                    const int gcol = cb0 + wn * 32 + ni * 16 + rr;
                    const float val = acc[mi][ni][r] * s;
                    const bool pos = (lr == lcv[ni]);
                    float ex = __expf(pos ? -val : val);
                    if (grow == gcol) ex = 0.f;       // self-pair (diag only)
                    if (pos) { rowA[mi][r] += ex; cA[ni] += ex; }
                    else     { rowB[mi][r] += ex; cB[ni] += ex; }
                }
            }
        }

        if (!diag) {   // col-side partials (transposed contribution)
            #pragma unroll
            for (int ni = 0; ni < 2; ++ni) {
                float a = cA[ni], b = cB[ni];
                a += __shfl_xor(a, 16); a += __shfl_xor(a, 32);
                b += __shfl_xor(b, 16); b += __shfl_xor(b, 32);
                if (lane < 16) {
                    colsc[li & 1][wm][wn * 32 + ni * 16 + lane][0] = a;
                    colsc[li & 1][wm][wn * 32 + ni * 16 + lane][1] = b;
                }
            }
        }
        __syncthreads();   // drains B prefetch (vmcnt) + colsc visible

        if (!diag && tid < CPAN) {
            float ca = 0.f, cb = 0.f;
            #pragma unroll
            for (int w = 0; w < 4; ++w) {
                ca += colsc[li & 1][w][tid][0];
                cb += colsc[li & 1][w][tid][1];
            }
            wsAB[(size_t)by * N_EMB + cb0 + tid] = packbf(ca, cb);
        }
    }

    // ---- run end: row side (one red16 + write per row) ----
    #pragma unroll
    for (int mi = 0; mi < 2; ++mi) {
        #pragma unroll
        for (int r = 0; r < 4; ++r) {
            const float ra = red16(rowA[mi][r]);
            const float rb = red16(rowB[mi][r]);
            if (rr == 0) {
                const int rowL = wm * 32 + mi * 16 + kh * 4 + r;
                rowsc[wn][rowL][0] = ra;
                rowsc[wn][rowL][1] = rb;
            }
        }
    }
    __syncthreads();
    if (tid < PAN) {
        const float ra = rowsc[0][tid][0] + rowsc[1][tid][0];
        const float rb = rowsc[0][tid][1] + rowsc[1][tid][1];
        wsAB[(size_t)bxFirst * N_EMB + rowBase + tid] = packbf(ra, rb);
    }
}

// --------------------------------------------------- per-row + segment reduce
__global__ __launch_bounds__(256) void reduce_rows(const unsigned* __restrict__ wsAB,
                                                   const int* __restrict__ labels,
                                                   float* __restrict__ part) {
    __shared__ float A[NUM_LABELS], B[NUM_LABELS];
    __shared__ int C[NUM_LABELS];
    const int tid = threadIdx.x;
    if (tid < NUM_LABELS) { A[tid] = 0.f; B[tid] = 0.f; C[tid] = 0; }
    __syncthreads();
    const int row = blockIdx.x * 256 + tid;
    float a = 0.f, b = 0.f;
    #pragma unroll
    for (int p = 0; p < NPAN; ++p) {
        const unsigned u = wsAB[(size_t)p * N_EMB + row];
        a += __builtin_bit_cast(float, u << 16);
        b += __builtin_bit_cast(float, u & 0xFFFF0000u);
    }
    const int l = labels[row];
    atomicAdd(&A[l], a);
    atomicAdd(&B[l], b);
    atomicAdd(&C[l], 1);
    __syncthreads();
    if (tid < NUM_LABELS) {
        float* p = part + ((size_t)blockIdx.x * NUM_LABELS + tid) * 3;
        p[0] = A[tid]; p[1] = B[tid]; p[2] = (float)C[tid];
    }
}

// ----------------------------------------------------------------- finalize
__global__ __launch_bounds__(128) void finalize_kernel(const float* __restrict__ part,
                                                       float* __restrict__ out) {
    const int tid = threadIdx.x;   // label id
    float A = 0.f, B = 0.f, c = 0.f;
    #pragma unroll
    for (int blk = 0; blk < 32; ++blk) {
        const float* p = part + ((size_t)blk * NUM_LABELS + tid) * 3;
        A += p[0]; B += p[1]; c += p[2];
    }
    float v = (c >= 2.f) ? A * B : 0.f;
    #pragma unroll
    for (int off = 32; off >= 1; off >>= 1) v += __shfl_xor(v, off);
    __shared__ float w2[2];
    if ((tid & 63) == 0) w2[tid >> 6] = v;
    __syncthreads();
    if (tid == 0) out[0] = logf(1.0f + w2[0] + w2[1]);
}

// ------------------------------------------------------------------ launcher
extern "C" void kernel_launch(void* const* d_in, const int* in_sizes, int n_in,
                              void* d_out, int out_size, void* d_ws, size_t ws_size,
                              hipStream_t stream) {
    const float* emb    = (const float*)d_in[0];
    const int*   labels = (const int*)d_in[1];
    const float* scale  = (const float*)d_in[2];
    float* out = (float*)d_out;

    bf16*     e16  = (bf16*)d_ws;                                     // 4 MB
    unsigned* wsAB = (unsigned*)((char*)d_ws + (size_t)N_EMB * D_EMB * sizeof(bf16)); // 2 MB
    float*    part = (float*)((char*)wsAB + (size_t)NPAN * N_EMB * sizeof(unsigned)); // 48 KB

    normalize_kernel<<<N_EMB / 4, 256, 0, stream>>>(emb, e16, wsAB);
    cosent_main<<<NRUN, 512, 0, stream>>>(e16, labels, scale, wsAB);
    reduce_rows<<<N_EMB / 256, 256, 0, stream>>>(wsAB, labels, part);
    finalize_kernel<<<1, 128, 0, stream>>>(part, out);
}

// Round 9
// 50.808 us; speedup vs baseline: 4.7685x; 1.4502x over previous
//
#include <hip/hip_runtime.h>
#include <hip/hip_bf16.h>
#include <math.h>

// CoSent clustering loss on MI355X — round 9.
// Key change: frag-major pre-layout of normalized embeddings (eF). Each MFMA
// fragment (16 rows x 32 k) is 1024 contiguous bytes in lane order, so an
// operand load is ONE fully-coalesced global_load_dwordx4 (16 sequential
// 64B lines) — eliminates the 16-scattered-line gather that throttled r3-r6
// and the LDS-pipe oversubscription of r8. No operand LDS at all.
// K-loop: register double-buffer, inline-asm loads, counted vmcnt(8).

typedef __bf16 bf16;
typedef __attribute__((ext_vector_type(8))) __bf16 bf16x8;
typedef __attribute__((ext_vector_type(4))) float f32x4;

#define N_EMB 8192
#define D_EMB 256
#define NUM_LABELS 128
#define PAN 128
#define NPAN (N_EMB / PAN)           // 64
#define NTRI (NPAN * (NPAN + 1) / 2) // 2080 = 8 * 260

// ---- DPP 16-lane reduction helpers ----
template <int CTRL>
__device__ __forceinline__ float dpp_add(float x) {
    int y = __builtin_amdgcn_update_dpp(0, __builtin_bit_cast(int, x),
                                        CTRL, 0xF, 0xF, false);
    return x + __builtin_bit_cast(float, y);
}
__device__ __forceinline__ float red16(float x) {
    x = dpp_add<0xB1>(x);    // quad_perm xor1
    x = dpp_add<0x4E>(x);    // quad_perm xor2
    x = dpp_add<0x124>(x);   // row_ror:4
    x = dpp_add<0x128>(x);   // row_ror:8
    return x;
}

__device__ __forceinline__ unsigned packbf(float a, float b) {
    unsigned ua = __builtin_bit_cast(unsigned, a);
    unsigned ub = __builtin_bit_cast(unsigned, b);
    ua += 0x7FFFu + ((ua >> 16) & 1u);   // RTNE to bf16
    ub += 0x7FFFu + ((ub >> 16) & 1u);
    return (ua >> 16) | (ub & 0xFFFF0000u);
}

// ---------------------------------------------------------------- normalize
// Writes eF in frag-major order: frag (g,t) = rows g*16..+15, k t*32..+31,
// at byte (g*8+t)*1024; within frag, lane l=(kh*16+rr) holds 16B.
// Lane here covers k = lane*4..+3 of one row -> 8B store at
// ((row>>4)*8 + (lane>>3))*1024 + (((lane>>1)&3)*16 + (row&15))*16 + (lane&1)*8.
__global__ __launch_bounds__(256) void normalize_kernel(const float* __restrict__ emb,
                                                        bf16* __restrict__ eF) {
    const int wid = threadIdx.x >> 6, lane = threadIdx.x & 63;
    const int row = blockIdx.x * 4 + wid;
    const f32x4 x = *(const f32x4*)(emb + (size_t)row * D_EMB + lane * 4);
    float ss = x[0]*x[0] + x[1]*x[1] + x[2]*x[2] + x[3]*x[3];
    #pragma unroll
    for (int off = 32; off >= 1; off >>= 1) ss += __shfl_xor(ss, off);
    const float r = 1.0f / fmaxf(sqrtf(ss), 1e-12f);
    unsigned b[4];
    #pragma unroll
    for (int i = 0; i < 4; ++i) {
        unsigned u = __builtin_bit_cast(unsigned, x[i] * r);
        u += 0x7FFFu + ((u >> 16) & 1u);      // RTNE to bf16
        b[i] = u >> 16;
    }
    uint2 o = { b[0] | (b[1] << 16), b[2] | (b[3] << 16) };
    const int t  = lane >> 3;
    const int fl = ((lane >> 1) & 3) * 16 + (row & 15);
    char* dst = (char*)eF + ((size_t)(row >> 4) * 8 + t) * 1024 + fl * 16 + (lane & 1) * 8;
    *(uint2*)dst = o;
}

// ---- pinned coalesced frag load: SGPR base + VGPR offset + literal imm ----
#define LOADF(dst, voff, sb, OFFSTR) \
    asm volatile("global_load_dwordx4 %0, %1, %2 offset:" OFFSTR \
                 : "=v"(dst) : "v"(voff), "s"(sb))

#define ISSUE(SA, SB_, VA_, VB_, OFFSTR) \
    LOADF(SA##0, VA_[0], sbA, OFFSTR); LOADF(SA##1, VA_[1], sbA, OFFSTR); \
    LOADF(SA##2, VA_[2], sbA, OFFSTR); LOADF(SA##3, VA_[3], sbA, OFFSTR); \
    LOADF(SB_##0, VB_[0], sbB, OFFSTR); LOADF(SB_##1, VB_[1], sbB, OFFSTR); \
    LOADF(SB_##2, VB_[2], sbB, OFFSTR); LOADF(SB_##3, VB_[3], sbB, OFFSTR)

#define WAITV(NSTR) \
    asm volatile("s_waitcnt vmcnt(" NSTR ")" ::: "memory"); \
    __builtin_amdgcn_sched_barrier(0)

#define MF(a, b, c) __builtin_amdgcn_mfma_f32_16x16x32_bf16( \
    __builtin_bit_cast(bf16x8, a), __builtin_bit_cast(bf16x8, b), c, 0, 0, 0)

#define MFMA16(SA, SB_) \
    __builtin_amdgcn_s_setprio(1); \
    acc[0][0]=MF(SA##0,SB_##0,acc[0][0]); acc[0][1]=MF(SA##0,SB_##1,acc[0][1]); \
    acc[0][2]=MF(SA##0,SB_##2,acc[0][2]); acc[0][3]=MF(SA##0,SB_##3,acc[0][3]); \
    acc[1][0]=MF(SA##1,SB_##0,acc[1][0]); acc[1][1]=MF(SA##1,SB_##1,acc[1][1]); \
    acc[1][2]=MF(SA##1,SB_##2,acc[1][2]); acc[1][3]=MF(SA##1,SB_##3,acc[1][3]); \
    acc[2][0]=MF(SA##2,SB_##0,acc[2][0]); acc[2][1]=MF(SA##2,SB_##1,acc[2][1]); \
    acc[2][2]=MF(SA##2,SB_##2,acc[2][2]); acc[2][3]=MF(SA##2,SB_##3,acc[2][3]); \
    acc[3][0]=MF(SA##3,SB_##0,acc[3][0]); acc[3][1]=MF(SA##3,SB_##1,acc[3][1]); \
    acc[3][2]=MF(SA##3,SB_##2,acc[3][2]); acc[3][3]=MF(SA##3,SB_##3,acc[3][3]); \
    __builtin_amdgcn_s_setprio(0)

// ----------------------------------------------------------------- main GEMM
// Triangular 128x128 tiles, 4 waves (2x2), per-wave 64x64 = 4x4 frags.
// Operands stream directly from frag-major eF (L2-resident), register
// double-buffered (P/Q), counted vmcnt(8) — never drained mid-loop.
__global__ __launch_bounds__(256, 3) void cosent_main(const bf16* __restrict__ eF,
                                                      const int* __restrict__ labels,
                                                      const float* __restrict__ scale,
                                                      unsigned* __restrict__ wsAB) {
    __shared__ float rowsc[2][PAN][2];
    __shared__ float colsc[2][PAN][2];
    __shared__ int labR[PAN], labC[PAN];

    // XCD-bijective swizzle (2080 = 8*260), then triangular decode (by <= bx)
    const int bid = blockIdx.x;
    const int swz = (bid & 7) * 260 + (bid >> 3);
    int rem = swz, by = 0;
    while (rem >= NPAN - by) { rem -= NPAN - by; ++by; }
    const int bx = by + rem;
    const bool diag = (bx == by);
    const int rowBase = by * PAN, colBase = bx * PAN;

    const int tid = threadIdx.x, lane = tid & 63, wid = tid >> 6;
    const int wm = wid >> 1, wn = wid & 1;
    const int rr = lane & 15, kh = lane >> 4;

    if (tid < PAN) labR[tid] = labels[rowBase + tid];
    else           labC[tid - PAN] = labels[colBase + tid - PAN];
    __syncthreads();                 // labels visible; vmem fully drained

    // per-frag voffsets (bytes): group (w*4+i) stride 8192, lane stride 16
    const int laneB = lane * 16;
    int voA[4], voA4[4], voB[4], voB4[4];
    #pragma unroll
    for (int i = 0; i < 4; ++i) {
        voA[i]  = (wm * 4 + i) * 8192 + laneB;  voA4[i] = voA[i] + 4096;
        voB[i]  = (wn * 4 + i) * 8192 + laneB;  voB4[i] = voB[i] + 4096;
    }
    const bf16* sbA = eF + (size_t)rowBase * 256;   // = byte rowBase*512
    const bf16* sbB = eF + (size_t)colBase * 256;

    f32x4 acc[4][4];
    #pragma unroll
    for (int i = 0; i < 4; ++i)
        #pragma unroll
        for (int j = 0; j < 4; ++j) acc[i][j] = (f32x4){0.f, 0.f, 0.f, 0.f};

    f32x4 pA0, pA1, pA2, pA3, pB0, pB1, pB2, pB3;
    f32x4 qA0, qA1, qA2, qA3, qB0, qB1, qB2, qB3;

    ISSUE(pA, pB, voA, voB, "0");                       // t=0
    ISSUE(qA, qB, voA, voB, "1024"); WAITV("8"); MFMA16(pA, pB);   // t=1 | t0
    ISSUE(pA, pB, voA, voB, "2048"); WAITV("8"); MFMA16(qA, qB);   // t=2 | t1
    ISSUE(qA, qB, voA, voB, "3072"); WAITV("8"); MFMA16(pA, pB);   // t=3 | t2
    ISSUE(pA, pB, voA4, voB4, "0");  WAITV("8"); MFMA16(qA, qB);   // t=4 | t3
    ISSUE(qA, qB, voA4, voB4, "1024"); WAITV("8"); MFMA16(pA, pB); // t=5 | t4
    ISSUE(pA, pB, voA4, voB4, "2048"); WAITV("8"); MFMA16(qA, qB); // t=6 | t5
    ISSUE(qA, qB, voA4, voB4, "3072"); WAITV("8"); MFMA16(pA, pB); // t=7 | t6
    WAITV("0"); MFMA16(qA, qB);                                    //     | t7

    // ------------- fused epilogue: one exp per element, row + col partials
    const float s = *scale;
    int lc[4];
    #pragma unroll
    for (int ni = 0; ni < 4; ++ni) lc[ni] = labC[wn * 64 + ni * 16 + rr];
    float colA[4] = {0.f, 0.f, 0.f, 0.f}, colB[4] = {0.f, 0.f, 0.f, 0.f};

    #pragma unroll
    for (int mi = 0; mi < 4; ++mi) {
        #pragma unroll
        for (int r = 0; r < 4; ++r) {
            const int rowL = wm * 64 + mi * 16 + kh * 4 + r;
            const int lr = labR[rowL];
            float asum = 0.f, bsum = 0.f;
            #pragma unroll
            for (int ni = 0; ni < 4; ++ni) {
                const int colL = wn * 64 + ni * 16 + rr;
                const float val = acc[mi][ni][r] * s;
                const bool pos = (lr == lc[ni]);
                float ex = __expf(pos ? -val : val);
                if (diag && rowL == colL) ex = 0.f;   // exclude self-pairs
                if (pos) { asum += ex; colA[ni] += ex; }
                else     { bsum += ex; colB[ni] += ex; }
            }
            asum = red16(asum);
            bsum = red16(bsum);
            if (rr == 0) { rowsc[wn][rowL][0] = asum; rowsc[wn][rowL][1] = bsum; }
        }
    }

    if (!diag) {   // col-side (transposed contribution via symmetry)
        #pragma unroll
        for (int ni = 0; ni < 4; ++ni) {
            float a = colA[ni], b = colB[ni];
            a += __shfl_xor(a, 16); a += __shfl_xor(a, 32);
            b += __shfl_xor(b, 16); b += __shfl_xor(b, 32);
            if (lane < 16) {
                colsc[wm][wn * 64 + ni * 16 + lane][0] = a;
                colsc[wm][wn * 64 + ni * 16 + lane][1] = b;
            }
        }
    }
    __syncthreads();

    if (tid < PAN) {
        const float ra = rowsc[0][tid][0] + rowsc[1][tid][0];
        const float rb = rowsc[0][tid][1] + rowsc[1][tid][1];
        wsAB[(size_t)bx * N_EMB + rowBase + tid] = packbf(ra, rb);
        if (!diag) {
            const float ca = colsc[0][tid][0] + colsc[1][tid][0];
            const float cb = colsc[0][tid][1] + colsc[1][tid][1];
            wsAB[(size_t)by * N_EMB + colBase + tid] = packbf(ca, cb);
        }
    }
}

// --------------------------------------------------- per-row + segment reduce
__global__ __launch_bounds__(256) void reduce_rows(const unsigned* __restrict__ wsAB,
                                                   const int* __restrict__ labels,
                                                   float* __restrict__ part) {
    __shared__ float A[NUM_LABELS], B[NUM_LABELS];
    __shared__ int C[NUM_LABELS];
    const int tid = threadIdx.x;
    if (tid < NUM_LABELS) { A[tid] = 0.f; B[tid] = 0.f; C[tid] = 0; }
    __syncthreads();
    const int row = blockIdx.x * 256 + tid;
    float a = 0.f, b = 0.f;
    #pragma unroll
    for (int p = 0; p < NPAN; ++p) {
        const unsigned u = wsAB[(size_t)p * N_EMB + row];
        a += __builtin_bit_cast(float, u << 16);
        b += __builtin_bit_cast(float, u & 0xFFFF0000u);
    }
    const int l = labels[row];
    atomicAdd(&A[l], a);
    atomicAdd(&B[l], b);
    atomicAdd(&C[l], 1);
    __syncthreads();
    if (tid < NUM_LABELS) {
        float* p = part + ((size_t)blockIdx.x * NUM_LABELS + tid) * 3;
        p[0] = A[tid]; p[1] = B[tid]; p[2] = (float)C[tid];
    }
}

// ----------------------------------------------------------------- finalize
__global__ __launch_bounds__(128) void finalize_kernel(const float* __restrict__ part,
                                                       float* __restrict__ out) {
    const int tid = threadIdx.x;   // label id
    float A = 0.f, B = 0.f, c = 0.f;
    #pragma unroll
    for (int blk = 0; blk < 32; ++blk) {
        const float* p = part + ((size_t)blk * NUM_LABELS + tid) * 3;
        A += p[0]; B += p[1]; c += p[2];
    }
    float v = (c >= 2.f) ? A * B : 0.f;
    #pragma unroll
    for (int off = 32; off >= 1; off >>= 1) v += __shfl_xor(v, off);
    __shared__ float w2[2];
    if ((tid & 63) == 0) w2[tid >> 6] = v;
    __syncthreads();
    if (tid == 0) out[0] = logf(1.0f + w2[0] + w2[1]);
}

// ------------------------------------------------------------------ launcher
extern "C" void kernel_launch(void* const* d_in, const int* in_sizes, int n_in,
                              void* d_out, int out_size, void* d_ws, size_t ws_size,
                              hipStream_t stream) {
    const float* emb    = (const float*)d_in[0];
    const int*   labels = (const int*)d_in[1];
    const float* scale  = (const float*)d_in[2];
    float* out = (float*)d_out;

    bf16*     eF   = (bf16*)d_ws;                                     // 4 MB (frag-major)
    unsigned* wsAB = (unsigned*)((char*)d_ws + (size_t)N_EMB * D_EMB * sizeof(bf16)); // 2 MB
    float*    part = (float*)((char*)wsAB + (size_t)NPAN * N_EMB * sizeof(unsigned)); // 48 KB

    normalize_kernel<<<N_EMB / 4, 256, 0, stream>>>(emb, eF);
    cosent_main<<<NTRI, 256, 0, stream>>>(eF, labels, scale, wsAB);
    reduce_rows<<<N_EMB / 256, 256, 0, stream>>>(wsAB, labels, part);
    finalize_kernel<<<1, 128, 0, stream>>>(part, out);
}

// Round 10
// 47.137 us; speedup vs baseline: 5.1399x; 1.0779x over previous
//
#include <hip/hip_runtime.h>
#include <hip/hip_bf16.h>
#include <math.h>

// CoSent clustering loss on MI355X — round 10.
// r9 (frag-major bf16, reg-dbuf, counted vmcnt) broke the 61us wall.
// r10: fp8-e4m3 operands at the same MFMA shape/rate — halves operand-stream
// bytes AND load-instruction count (superfrag layout: one dwordx4 = two
// 16x16x32 fp8 fragments). Tolerance analysis: threshold 0.557 on log-output,
// fp8 gives ~0.02-0.04 — 15x margin.

typedef __attribute__((ext_vector_type(2))) long l2;     // two fp8 frags
typedef __attribute__((ext_vector_type(4))) float f32x4;

#define N_EMB 8192
#define D_EMB 256
#define NUM_LABELS 128
#define PAN 128
#define NPAN (N_EMB / PAN)           // 64
#define NTRI (NPAN * (NPAN + 1) / 2) // 2080 = 8 * 260

// ---- DPP 16-lane reduction helpers ----
template <int CTRL>
__device__ __forceinline__ float dpp_add(float x) {
    int y = __builtin_amdgcn_update_dpp(0, __builtin_bit_cast(int, x),
                                        CTRL, 0xF, 0xF, false);
    return x + __builtin_bit_cast(float, y);
}
__device__ __forceinline__ float red16(float x) {
    x = dpp_add<0xB1>(x);    // quad_perm xor1
    x = dpp_add<0x4E>(x);    // quad_perm xor2
    x = dpp_add<0x124>(x);   // row_ror:4
    x = dpp_add<0x128>(x);   // row_ror:8
    return x;
}

__device__ __forceinline__ unsigned packbf(float a, float b) {
    unsigned ua = __builtin_bit_cast(unsigned, a);
    unsigned ub = __builtin_bit_cast(unsigned, b);
    ua += 0x7FFFu + ((ua >> 16) & 1u);   // RTNE to bf16
    ub += 0x7FFFu + ((ub >> 16) & 1u);
    return (ua >> 16) | (ub & 0xFFFF0000u);
}

// ---------------------------------------------------------------- normalize
// Emits fp8 in superfrag-major order. Superfrag (g,u): rows g*16..+15,
// k = u*64..+63, 1024 B at ((g*4)+u)*1024. Lane l' of the consuming wave
// holds 16 B at l'*16: bytes 0-7 = k u*64+(l'>>4)*8+j, bytes 8-15 =
// k u*64+32+(l'>>4)*8+j, row = g*16 + (l'&15).
// Here: 1 wave per row, lane covers k = lane*4..+3 -> one dword store.
__global__ __launch_bounds__(256) void normalize_kernel(const float* __restrict__ emb,
                                                        char* __restrict__ e8) {
    const int wid = threadIdx.x >> 6, lane = threadIdx.x & 63;
    const int row = blockIdx.x * 4 + wid;
    const f32x4 x = *(const f32x4*)(emb + (size_t)row * D_EMB + lane * 4);
    float ss = x[0]*x[0] + x[1]*x[1] + x[2]*x[2] + x[3]*x[3];
    #pragma unroll
    for (int off = 32; off >= 1; off >>= 1) ss += __shfl_xor(ss, off);
    const float r = 1.0f / fmaxf(sqrtf(ss), 1e-12f);
    int v = __builtin_amdgcn_cvt_pk_fp8_f32(x[0] * r, x[1] * r, 0, false);
    v = __builtin_amdgcn_cvt_pk_fp8_f32(x[2] * r, x[3] * r, v, true);
    const int u    = lane >> 4;
    const int half = (lane >> 3) & 1;
    const int lp   = ((lane >> 1) & 3) * 16 + (row & 15);
    const int j0   = (lane & 1) * 4;
    char* dst = e8 + ((size_t)(row >> 4) * 4 + u) * 1024 + lp * 16 + half * 8 + j0;
    *(unsigned*)dst = (unsigned)v;
}

// ---- pinned coalesced superfrag load: SGPR base + VGPR offset + literal ----
#define LOADF(dst, voff, sb, OFFSTR) \
    asm volatile("global_load_dwordx4 %0, %1, %2 offset:" OFFSTR \
                 : "=v"(dst) : "v"(voff), "s"(sb))

#define ISSUE(PA_, PB_, OFFSTR) \
    LOADF(PA_[0], voA[0], sbA, OFFSTR); LOADF(PA_[1], voA[1], sbA, OFFSTR); \
    LOADF(PA_[2], voA[2], sbA, OFFSTR); LOADF(PA_[3], voA[3], sbA, OFFSTR); \
    LOADF(PB_[0], voB[0], sbB, OFFSTR); LOADF(PB_[1], voB[1], sbB, OFFSTR); \
    LOADF(PB_[2], voB[2], sbB, OFFSTR); LOADF(PB_[3], voB[3], sbB, OFFSTR)

#define WAITV(NSTR) \
    asm volatile("s_waitcnt vmcnt(" NSTR ")" ::: "memory"); \
    __builtin_amdgcn_sched_barrier(0)

#define MF8(a, b, c) __builtin_amdgcn_mfma_f32_16x16x32_fp8_fp8(a, b, c, 0, 0, 0)

#define MROW(PA_, PB_, mi, H) \
    acc[mi][0] = MF8(PA_[mi][H], PB_[0][H], acc[mi][0]); \
    acc[mi][1] = MF8(PA_[mi][H], PB_[1][H], acc[mi][1]); \
    acc[mi][2] = MF8(PA_[mi][H], PB_[2][H], acc[mi][2]); \
    acc[mi][3] = MF8(PA_[mi][H], PB_[3][H], acc[mi][3]);

#define MFMA32(PA_, PB_) \
    __builtin_amdgcn_s_setprio(1); \
    MROW(PA_, PB_, 0, 0) MROW(PA_, PB_, 1, 0) MROW(PA_, PB_, 2, 0) MROW(PA_, PB_, 3, 0) \
    MROW(PA_, PB_, 0, 1) MROW(PA_, PB_, 1, 1) MROW(PA_, PB_, 2, 1) MROW(PA_, PB_, 3, 1) \
    __builtin_amdgcn_s_setprio(0)

// ----------------------------------------------------------------- main GEMM
// Triangular 128x128 tiles, 4 waves (2x2), per-wave 64x64 = 4x4 frags.
// Operands stream from superfrag-major fp8 (L2-resident), register
// double-buffered (P/Q), counted vmcnt(8); 4 K-steps of 32 MFMAs.
__global__ __launch_bounds__(256, 3) void cosent_main(const char* __restrict__ e8,
                                                      const int* __restrict__ labels,
                                                      const float* __restrict__ scale,
                                                      unsigned* __restrict__ wsAB) {
    __shared__ float rowsc[2][PAN][2];
    __shared__ float colsc[2][PAN][2];
    __shared__ int labR[PAN], labC[PAN];

    // XCD-bijective swizzle (2080 = 8*260), then triangular decode (by <= bx)
    const int bid = blockIdx.x;
    const int swz = (bid & 7) * 260 + (bid >> 3);
    int rem = swz, by = 0;
    while (rem >= NPAN - by) { rem -= NPAN - by; ++by; }
    const int bx = by + rem;
    const bool diag = (bx == by);
    const int rowBase = by * PAN, colBase = bx * PAN;

    const int tid = threadIdx.x, lane = tid & 63, wid = tid >> 6;
    const int wm = wid >> 1, wn = wid & 1;
    const int rr = lane & 15, kh = lane >> 4;

    if (tid < PAN) labR[tid] = labels[rowBase + tid];
    else           labC[tid - PAN] = labels[colBase + tid - PAN];
    __syncthreads();

    // per-frag-group voffsets (bytes): group (w*4+i) stride 4096, lane 16B
    const int laneB = lane * 16;
    int voA[4], voB[4];
    #pragma unroll
    for (int i = 0; i < 4; ++i) {
        voA[i] = (wm * 4 + i) * 4096 + laneB;
        voB[i] = (wn * 4 + i) * 4096 + laneB;
    }
    const char* sbA = e8 + (size_t)rowBase * 256;   // byte base of row panel
    const char* sbB = e8 + (size_t)colBase * 256;

    f32x4 acc[4][4];
    #pragma unroll
    for (int i = 0; i < 4; ++i)
        #pragma unroll
        for (int j = 0; j < 4; ++j) acc[i][j] = (f32x4){0.f, 0.f, 0.f, 0.f};

    l2 pA[4], pB[4], qA[4], qB[4];

    ISSUE(pA, pB, "0");                                   // u=0
    ISSUE(qA, qB, "1024"); WAITV("8"); MFMA32(pA, pB);    // u=1 | u0
    ISSUE(pA, pB, "2048"); WAITV("8"); MFMA32(qA, qB);    // u=2 | u1
    ISSUE(qA, qB, "3072"); WAITV("8"); MFMA32(pA, pB);    // u=3 | u2
    WAITV("0"); MFMA32(qA, qB);                           //     | u3

    // ------------- fused epilogue: one exp per element, row + col partials
    const float s = *scale;
    int lc[4];
    #pragma unroll
    for (int ni = 0; ni < 4; ++ni) lc[ni] = labC[wn * 64 + ni * 16 + rr];
    float colA[4] = {0.f, 0.f, 0.f, 0.f}, colB[4] = {0.f, 0.f, 0.f, 0.f};

    #pragma unroll
    for (int mi = 0; mi < 4; ++mi) {
        #pragma unroll
        for (int r = 0; r < 4; ++r) {
            const int rowL = wm * 64 + mi * 16 + kh * 4 + r;
            const int lr = labR[rowL];
            float asum = 0.f, bsum = 0.f;
            #pragma unroll
            for (int ni = 0; ni < 4; ++ni) {
                const int colL = wn * 64 + ni * 16 + rr;
                const float val = acc[mi][ni][r] * s;
                const bool pos = (lr == lc[ni]);
                float ex = __expf(pos ? -val : val);
                if (diag && rowL == colL) ex = 0.f;   // exclude self-pairs
                if (pos) { asum += ex; colA[ni] += ex; }
                else     { bsum += ex; colB[ni] += ex; }
            }
            asum = red16(asum);
            bsum = red16(bsum);
            if (rr == 0) { rowsc[wn][rowL][0] = asum; rowsc[wn][rowL][1] = bsum; }
        }
    }

    if (!diag) {   // col-side (transposed contribution via symmetry)
        #pragma unroll
        for (int ni = 0; ni < 4; ++ni) {
            float a = colA[ni], b = colB[ni];
            a += __shfl_xor(a, 16); a += __shfl_xor(a, 32);
            b += __shfl_xor(b, 16); b += __shfl_xor(b, 32);
            if (lane < 16) {
                colsc[wm][wn * 64 + ni * 16 + lane][0] = a;
                colsc[wm][wn * 64 + ni * 16 + lane][1] = b;
            }
        }
    }
    __syncthreads();

    if (tid < PAN) {
        const float ra = rowsc[0][tid][0] + rowsc[1][tid][0];
        const float rb = rowsc[0][tid][1] + rowsc[1][tid][1];
        wsAB[(size_t)bx * N_EMB + rowBase + tid] = packbf(ra, rb);
        if (!diag) {
            const float ca = colsc[0][tid][0] + colsc[1][tid][0];
            const float cb = colsc[0][tid][1] + colsc[1][tid][1];
            wsAB[(size_t)by * N_EMB + colBase + tid] = packbf(ca, cb);
        }
    }
}

// --------------------------------------------------- per-row + segment reduce
__global__ __launch_bounds__(256) void reduce_rows(const unsigned* __restrict__ wsAB,
                                                   const int* __restrict__ labels,
                                                   float* __restrict__ part) {
    __shared__ float A[NUM_LABELS], B[NUM_LABELS];
    __shared__ int C[NUM_LABELS];
    const int tid = threadIdx.x;
    if (tid < NUM_LABELS) { A[tid] = 0.f; B[tid] = 0.f; C[tid] = 0; }
    __syncthreads();
    const int row = blockIdx.x * 256 + tid;
    float a = 0.f, b = 0.f;
    #pragma unroll
    for (int p = 0; p < NPAN; ++p) {
        const unsigned u = wsAB[(size_t)p * N_EMB + row];
        a += __builtin_bit_cast(float, u << 16);
        b += __builtin_bit_cast(float, u & 0xFFFF0000u);
    }
    const int l = labels[row];
    atomicAdd(&A[l], a);
    atomicAdd(&B[l], b);
    atomicAdd(&C[l], 1);
    __syncthreads();
    if (tid < NUM_LABELS) {
        float* p = part + ((size_t)blockIdx.x * NUM_LABELS + tid) * 3;
        p[0] = A[tid]; p[1] = B[tid]; p[2] = (float)C[tid];
    }
}

// ----------------------------------------------------------------- finalize
__global__ __launch_bounds__(128) void finalize_kernel(const float* __restrict__ part,
                                                       float* __restrict__ out) {
    const int tid = threadIdx.x;   // label id
    float A = 0.f, B = 0.f, c = 0.f;
    #pragma unroll
    for (int blk = 0; blk < 32; ++blk) {
        const float* p = part + ((size_t)blk * NUM_LABELS + tid) * 3;
        A += p[0]; B += p[1]; c += p[2];
    }
    float v = (c >= 2.f) ? A * B : 0.f;
    #pragma unroll
    for (int off = 32; off >= 1; off >>= 1) v += __shfl_xor(v, off);
    __shared__ float w2[2];
    if ((tid & 63) == 0) w2[tid >> 6] = v;
    __syncthreads();
    if (tid == 0) out[0] = logf(1.0f + w2[0] + w2[1]);
}

// ------------------------------------------------------------------ launcher
extern "C" void kernel_launch(void* const* d_in, const int* in_sizes, int n_in,
                              void* d_out, int out_size, void* d_ws, size_t ws_size,
                              hipStream_t stream) {
    const float* emb    = (const float*)d_in[0];
    const int*   labels = (const int*)d_in[1];
    const float* scale  = (const float*)d_in[2];
    float* out = (float*)d_out;

    char*     e8   = (char*)d_ws;                                      // 2 MB (superfrag fp8)
    unsigned* wsAB = (unsigned*)((char*)d_ws + (size_t)N_EMB * D_EMB); // 2 MB
    float*    part = (float*)((char*)wsAB + (size_t)NPAN * N_EMB * sizeof(unsigned)); // 48 KB

    normalize_kernel<<<N_EMB / 4, 256, 0, stream>>>(emb, e8);
    cosent_main<<<NTRI, 256, 0, stream>>>(e8, labels, scale, wsAB);
    reduce_rows<<<N_EMB / 256, 256, 0, stream>>>(wsAB, labels, part);
    finalize_kernel<<<1, 128, 0, stream>>>(part, out);
}